// Round 4
// baseline (668.769 us; speedup 1.0000x reference)
//
#include <hip/hip_runtime.h>
#include <hip/hip_bf16.h>
#include <stdint.h>

#define DD 32   // input dim
#define HH 64   // hidden dim
#define ROWS 4  // batch rows per block (M=16 MFMA tile, rows 4-15 duplicated)
#define LOG2E 1.44269504088896340736f

typedef float f32x4 __attribute__((ext_vector_type(4)));
typedef short s16x8 __attribute__((ext_vector_type(8)));

__device__ __forceinline__ uint32_t pk2(float lo, float hi) {
  __hip_bfloat162 t = __float22bfloat162_rn(make_float2(lo, hi));
  union { __hip_bfloat162 b; uint32_t u; } v; v.b = t;
  return v.u;
}
__device__ __forceinline__ uint16_t f2bf(float f) {
  __hip_bfloat16 hb = __float2bfloat16(f);
  union { __hip_bfloat16 b; uint16_t u; } cv; cv.b = hb;
  return cv.u;
}

// Relaxed workgroup barrier: order LDS ops only; x-prefetch global loads stay
// in flight across timestep boundaries.
#define BAR() asm volatile("s_waitcnt lgkmcnt(0)\n\ts_barrier" ::: "memory")

__global__ __launch_bounds__(256, 2)
void lstm_fused(const float* __restrict__ x,
                const float* __restrict__ W_ih,
                const float* __restrict__ W_hh,
                const float* __restrict__ b_ih,
                const float* __restrict__ b_hh,
                const float* __restrict__ fc_W,
                const float* __restrict__ fc_b,
                float* __restrict__ out,
                int T)
{
  const int tid  = threadIdx.x;
  const int g    = tid >> 6;     // wave 0..3 -> 16-column gate group
  const int lane = tid & 63;
  const int lr   = lane & 15;    // A/D col index; also source lane for shfl
  const int lq   = lane >> 4;    // k-group 0..3; also this lane's cell row
  const int bm   = blockIdx.x * ROWS;
  const int arow = lr & 3;       // h/x row this lane loads (rows duplicated x4)

  __shared__ __align__(16) uint16_t hbuf[2][ROWS * 64]; // bf16 h, dbuf, XOR-swizzled

  // ---- persistent weights as B fragments, pre-scaled by log2e (2*log2e for g-gate) ----
  const int h0 = 16 * g + lr;
  s16x8 Bx[4], Bh0[4], Bh1[4];
  f32x4 biasv[4];
  #pragma unroll
  for (int j = 0; j < 4; ++j) {
    const int n = 64 * j + h0;
    const float sc = (j == 2) ? (2.0f * LOG2E) : LOG2E;
    {
      const float* p = W_ih + n * DD + lq * 8;
      f32x4 a = *(const f32x4*)p;
      f32x4 b = *(const f32x4*)(p + 4);
      union { uint32_t u[4]; s16x8 s; } pk;
      pk.u[0] = pk2(a[0]*sc, a[1]*sc); pk.u[1] = pk2(a[2]*sc, a[3]*sc);
      pk.u[2] = pk2(b[0]*sc, b[1]*sc); pk.u[3] = pk2(b[2]*sc, b[3]*sc);
      Bx[j] = pk.s;
    }
    {
      const float* p = W_hh + n * HH + lq * 8;
      f32x4 a = *(const f32x4*)p;
      f32x4 b = *(const f32x4*)(p + 4);
      union { uint32_t u[4]; s16x8 s; } pk;
      pk.u[0] = pk2(a[0]*sc, a[1]*sc); pk.u[1] = pk2(a[2]*sc, a[3]*sc);
      pk.u[2] = pk2(b[0]*sc, b[1]*sc); pk.u[3] = pk2(b[2]*sc, b[3]*sc);
      Bh0[j] = pk.s;
    }
    {
      const float* p = W_hh + n * HH + 32 + lq * 8;
      f32x4 a = *(const f32x4*)p;
      f32x4 b = *(const f32x4*)(p + 4);
      union { uint32_t u[4]; s16x8 s; } pk;
      pk.u[0] = pk2(a[0]*sc, a[1]*sc); pk.u[1] = pk2(a[2]*sc, a[3]*sc);
      pk.u[2] = pk2(b[0]*sc, b[1]*sc); pk.u[3] = pk2(b[2]*sc, b[3]*sc);
      Bh1[j] = pk.s;
    }
    const float bb = (b_ih[n] + b_hh[n]) * sc;
    biasv[j] = (f32x4){bb, bb, bb, bb};
  }

  for (int i = tid; i < 2 * ROWS * 64; i += 256) ((uint16_t*)hbuf)[i] = 0;

  float c = 0.f;  // this lane's single cell state: (row=lq, col=h0)

  // 2-deep x prefetch; rows duplicated 4x (coalescer dedups same-address lanes)
  const float* xbase = x + (size_t)(bm + arow) * (size_t)T * DD + lq * 8;
  f32x4 xa0 = *(const f32x4*)xbase;
  f32x4 xb0 = *(const f32x4*)(xbase + 4);
  f32x4 xa1 = *(const f32x4*)(xbase + DD);
  f32x4 xb1 = *(const f32x4*)(xbase + DD + 4);

  __syncthreads();

  auto step = [&](f32x4& xa, f32x4& xb, int tpre,
                  const uint16_t* __restrict__ hr, uint16_t* __restrict__ hw) {
    union { uint32_t u[4]; s16x8 s; } ax;
    ax.u[0] = pk2(xa[0], xa[1]); ax.u[1] = pk2(xa[2], xa[3]);
    ax.u[2] = pk2(xb[0], xb[1]); ax.u[3] = pk2(xb[2], xb[3]);
    f32x4 acc[4];
    #pragma unroll
    for (int j = 0; j < 4; ++j)
      acc[j] = __builtin_amdgcn_mfma_f32_16x16x32_bf16(ax.s, Bx[j], biasv[j], 0, 0, 0);

    BAR();  // lgkmcnt-only: prev step's h writes visible, x loads stay in flight

    {
      const size_t off = (size_t)tpre * DD;
      xa = *(const f32x4*)(xbase + off);
      xb = *(const f32x4*)(xbase + off + 4);
    }

    s16x8 ah0 = *(const s16x8*)(hr + arow * 64 + (((lq    ) ^ arow) << 3));
    s16x8 ah1 = *(const s16x8*)(hr + arow * 64 + (((lq + 4) ^ arow) << 3));
    #pragma unroll
    for (int j = 0; j < 4; ++j)
      acc[j] = __builtin_amdgcn_mfma_f32_16x16x32_bf16(ah0, Bh0[j], acc[j], 0, 0, 0);
    #pragma unroll
    for (int j = 0; j < 4; ++j)
      acc[j] = __builtin_amdgcn_mfma_f32_16x16x32_bf16(ah1, Bh1[j], acc[j], 0, 0, 0);

    // redistribute gates: lane owns cell (row=lq, col=h0). Value (row r, col
    // 16g+lr) lives in lane lr (lanes 0-15 hold valid rows 0-3), reg acc[j][r].
    float gate[4];
    #pragma unroll
    for (int j = 0; j < 4; ++j) {
      float t0 = __shfl(acc[j][0], lr);
      float t1 = __shfl(acc[j][1], lr);
      float t2 = __shfl(acc[j][2], lr);
      float t3 = __shfl(acc[j][3], lr);
      gate[j] = (lq == 0) ? t0 : (lq == 1) ? t1 : (lq == 2) ? t2 : t3;
    }

    // single-cell LSTM update (weights pre-scaled by log2e)
    float ig = __builtin_amdgcn_rcpf(1.f + __builtin_amdgcn_exp2f(-gate[0]));
    float fg = __builtin_amdgcn_rcpf(1.f + __builtin_amdgcn_exp2f(-gate[1]));
    float gt = 1.f - 2.f * __builtin_amdgcn_rcpf(1.f + __builtin_amdgcn_exp2f(gate[2]));
    float og = __builtin_amdgcn_rcpf(1.f + __builtin_amdgcn_exp2f(-gate[3]));
    c = fg * c + ig * gt;
    float tc = 1.f - 2.f * __builtin_amdgcn_rcpf(
                 1.f + __builtin_amdgcn_exp2f((2.0f * LOG2E) * c));
    float hv = og * tc;
    // swizzled store: elem = row*64 + ((col>>3)^row)*8 + (col&7)
    hw[lq * 64 + ((((h0 >> 3) ^ lq)) << 3) + (h0 & 7)] = f2bf(hv);
  };

  for (int t = 0; t < T; t += 2) {
    int p0 = (t + 2 < T) ? (t + 2) : (T - 1);
    int p1 = (t + 3 < T) ? (t + 3) : (T - 1);
    step(xa0, xb0, p0, hbuf[0], hbuf[1]);
    step(xa1, xb1, p1, hbuf[1], hbuf[0]);
  }

  __syncthreads();  // final h (bf16) in hbuf[0]

  // ---- epilogue: logits = h_last @ fc_W^T + fc_b ----
  if (tid < ROWS * 10) {
    const int m = tid / 10, cl = tid % 10;
    float s = fc_b[cl];
    const float* wr = fc_W + cl * HH;
    #pragma unroll
    for (int k = 0; k < HH; ++k) {
      union { uint32_t u; float f; } v;
      v.u = (uint32_t)hbuf[0][m * 64 + (((k >> 3) ^ m) << 3) + (k & 7)] << 16;
      s += v.f * wr[k];
    }
    out[(size_t)(bm + m) * 10 + cl] = s;
  }
}

extern "C" void kernel_launch(void* const* d_in, const int* in_sizes, int n_in,
                              void* d_out, int out_size, void* d_ws, size_t ws_size,
                              hipStream_t stream) {
  const float* x    = (const float*)d_in[0];
  const float* W_ih = (const float*)d_in[1];
  const float* W_hh = (const float*)d_in[2];
  const float* b_ih = (const float*)d_in[3];
  const float* b_hh = (const float*)d_in[4];
  const float* fc_W = (const float*)d_in[5];
  const float* fc_b = (const float*)d_in[6];
  float* out = (float*)d_out;

  const int B = out_size / 10;            // 2048
  const int T = in_sizes[0] / (B * DD);   // 1024

  dim3 grid(B / ROWS), block(256);
  hipLaunchKernelGGL(lstm_fused, grid, block, 0, stream,
                     x, W_ih, W_hh, b_ih, b_hh, fc_W, fc_b, out, T);
}

// Round 5
// 484.939 us; speedup vs baseline: 1.3791x; 1.3791x over previous
//
#include <hip/hip_runtime.h>
#include <hip/hip_bf16.h>
#include <stdint.h>

#define DD 32       // input dim
#define HH 64       // hidden dim
#define ROWS 4      // batch rows per block (M=16 MFMA tile, A-rows duplicated x4)
#define HSTRIDE 80  // LDS h-row stride in elems (160B: 16B-aligned, 2-way-bank-optimal)
#define LOG2E 1.44269504088896340736f

typedef float f32x4 __attribute__((ext_vector_type(4)));
typedef short s16x8 __attribute__((ext_vector_type(8)));

__device__ __forceinline__ uint32_t pk2(float lo, float hi) {
  __hip_bfloat162 t = __float22bfloat162_rn(make_float2(lo, hi));
  union { __hip_bfloat162 b; uint32_t u; } v; v.b = t;
  return v.u;
}
__device__ __forceinline__ uint16_t f2bf(float f) {
  __hip_bfloat16 hb = __float2bfloat16(f);
  union { __hip_bfloat16 b; uint16_t u; } cv; cv.b = hb;
  return cv.u;
}

// Relaxed workgroup barrier: order LDS ops only; x-prefetch global loads stay
// in flight across timestep boundaries.
#define BAR() asm volatile("s_waitcnt lgkmcnt(0)\n\ts_barrier" ::: "memory")

__global__ __launch_bounds__(256, 2)
void lstm_fused(const float* __restrict__ x,
                const float* __restrict__ W_ih,
                const float* __restrict__ W_hh,
                const float* __restrict__ b_ih,
                const float* __restrict__ b_hh,
                const float* __restrict__ fc_W,
                const float* __restrict__ fc_b,
                float* __restrict__ out,
                int T)
{
  const int tid  = threadIdx.x;
  const int g    = tid >> 6;     // wave 0..3 -> 16-column gate group
  const int lane = tid & 63;
  const int lr   = lane & 15;    // A/D col index within tile
  const int lq   = lane >> 4;    // k-group 0..3; ALSO this lane's assigned cell row
  const int bm   = blockIdx.x * ROWS;
  const int arow = lr & 3;       // batch row this lane's A-slot holds (dup x4)

  __shared__ __align__(16) uint16_t hbuf[2][ROWS * HSTRIDE]; // bf16 h, dbuf, XOR-swizzled

  // ---- persistent weights as B fragments, pre-scaled by log2e (2*log2e for g-gate) ----
  const int h0 = 16 * g + lr;    // this lane's hidden column
  s16x8 Bx[4], Bh0[4], Bh1[4];
  f32x4 biasv[4];
  #pragma unroll
  for (int j = 0; j < 4; ++j) {
    const int n = 64 * j + h0;   // gate j, hidden col h0
    const float sc = (j == 2) ? (2.0f * LOG2E) : LOG2E;
    {
      const float* p = W_ih + n * DD + lq * 8;
      f32x4 a = *(const f32x4*)p;
      f32x4 b = *(const f32x4*)(p + 4);
      union { uint32_t u[4]; s16x8 s; } pk;
      pk.u[0] = pk2(a[0]*sc, a[1]*sc); pk.u[1] = pk2(a[2]*sc, a[3]*sc);
      pk.u[2] = pk2(b[0]*sc, b[1]*sc); pk.u[3] = pk2(b[2]*sc, b[3]*sc);
      Bx[j] = pk.s;
    }
    {
      const float* p = W_hh + n * HH + lq * 8;
      f32x4 a = *(const f32x4*)p;
      f32x4 b = *(const f32x4*)(p + 4);
      union { uint32_t u[4]; s16x8 s; } pk;
      pk.u[0] = pk2(a[0]*sc, a[1]*sc); pk.u[1] = pk2(a[2]*sc, a[3]*sc);
      pk.u[2] = pk2(b[0]*sc, b[1]*sc); pk.u[3] = pk2(b[2]*sc, b[3]*sc);
      Bh0[j] = pk.s;
    }
    {
      const float* p = W_hh + n * HH + 32 + lq * 8;
      f32x4 a = *(const f32x4*)p;
      f32x4 b = *(const f32x4*)(p + 4);
      union { uint32_t u[4]; s16x8 s; } pk;
      pk.u[0] = pk2(a[0]*sc, a[1]*sc); pk.u[1] = pk2(a[2]*sc, a[3]*sc);
      pk.u[2] = pk2(b[0]*sc, b[1]*sc); pk.u[3] = pk2(b[2]*sc, b[3]*sc);
      Bh1[j] = pk.s;
    }
    const float bb = (b_ih[n] + b_hh[n]) * sc;
    biasv[j] = (f32x4){bb, bb, bb, bb};
  }

  for (int i = tid; i < 2 * ROWS * HSTRIDE; i += 256) ((uint16_t*)hbuf)[i] = 0;

  float c = 0.f;  // this lane's single cell: (row=lq, col=h0)

  // 2-deep x prefetch; addresses duplicated x4 across lq-groups (coalescer dedups)
  const float* xbase = x + (size_t)(bm + arow) * (size_t)T * DD + lq * 8;
  f32x4 xa0 = *(const f32x4*)xbase;
  f32x4 xb0 = *(const f32x4*)(xbase + 4);
  f32x4 xa1 = *(const f32x4*)(xbase + DD);
  f32x4 xb1 = *(const f32x4*)(xbase + DD + 4);

  __syncthreads();

  auto step = [&](f32x4& xa, f32x4& xb, int tpre,
                  const uint16_t* __restrict__ hr, uint16_t* __restrict__ hw) {
    // pack current x into A fragment, then immediately issue t+2 prefetch
    union { uint32_t u[4]; s16x8 s; } ax;
    ax.u[0] = pk2(xa[0], xa[1]); ax.u[1] = pk2(xa[2], xa[3]);
    ax.u[2] = pk2(xb[0], xb[1]); ax.u[3] = pk2(xb[2], xb[3]);
    {
      const size_t off = (size_t)tpre * DD;
      xa = *(const f32x4*)(xbase + off);
      xb = *(const f32x4*)(xbase + off + 4);
    }
    // x-part MFMAs (h-independent; overlap other waves' tail of prev step)
    f32x4 acc[4];
    #pragma unroll
    for (int j = 0; j < 4; ++j)
      acc[j] = __builtin_amdgcn_mfma_f32_16x16x32_bf16(ax.s, Bx[j], biasv[j], 0, 0, 0);

    BAR();  // lgkmcnt-only: prev step's h writes visible, x loads stay in flight

    // A_h fragments: row arow, k-chunks lq and lq+4 (XOR-swizzled, stride 80)
    s16x8 ah0 = *(const s16x8*)(hr + arow * HSTRIDE + (((lq    ) ^ arow) << 3));
    s16x8 ah1 = *(const s16x8*)(hr + arow * HSTRIDE + (((lq + 4) ^ arow) << 3));
    #pragma unroll
    for (int j = 0; j < 4; ++j)
      acc[j] = __builtin_amdgcn_mfma_f32_16x16x32_bf16(ah0, Bh0[j], acc[j], 0, 0, 0);
    #pragma unroll
    for (int j = 0; j < 4; ++j)
      acc[j] = __builtin_amdgcn_mfma_f32_16x16x32_bf16(ah1, Bh1[j], acc[j], 0, 0, 0);

    // acc[j][r] = gate j, batch row r, col h0 — identical across lq groups
    // (A-rows duplicated x4). Lane's assigned cell: (row lq, col h0).
    // Select acc[j][lq] with a cndmask tree (static reg indices, no divergence).
    float gj[4];
    #pragma unroll
    for (int j = 0; j < 4; ++j) {
      float s01 = (lq & 1) ? acc[j][1] : acc[j][0];
      float s23 = (lq & 1) ? acc[j][3] : acc[j][2];
      gj[j] = (lq & 2) ? s23 : s01;
    }

    // single-cell LSTM update (weights pre-scaled by log2e)
    float ig = __builtin_amdgcn_rcpf(1.f + __builtin_amdgcn_exp2f(-gj[0]));
    float fg = __builtin_amdgcn_rcpf(1.f + __builtin_amdgcn_exp2f(-gj[1]));
    float gt = 1.f - 2.f * __builtin_amdgcn_rcpf(1.f + __builtin_amdgcn_exp2f(gj[2]));
    float og = __builtin_amdgcn_rcpf(1.f + __builtin_amdgcn_exp2f(-gj[3]));
    c = fg * c + ig * gt;
    float tc = 1.f - 2.f * __builtin_amdgcn_rcpf(
                 1.f + __builtin_amdgcn_exp2f((2.0f * LOG2E) * c));
    float hv = og * tc;
    // one write per lane: h(row lq, col h0), swizzled
    hw[lq * HSTRIDE + ((((h0 >> 3) ^ lq)) << 3) + (h0 & 7)] = f2bf(hv);
  };

  for (int t = 0; t < T; t += 2) {
    int p0 = (t + 2 < T) ? (t + 2) : (T - 1);
    int p1 = (t + 3 < T) ? (t + 3) : (T - 1);
    step(xa0, xb0, p0, hbuf[0], hbuf[1]);
    step(xa1, xb1, p1, hbuf[1], hbuf[0]);
  }

  __syncthreads();  // final h (bf16) in hbuf[0]

  // ---- epilogue: logits = h_last @ fc_W^T + fc_b ----
  if (tid < ROWS * 10) {
    const int m = tid / 10, cl = tid % 10;
    float s = fc_b[cl];
    const float* wr = fc_W + cl * HH;
    #pragma unroll
    for (int k = 0; k < HH; ++k) {
      union { uint32_t u; float f; } v;
      v.u = (uint32_t)hbuf[0][m * HSTRIDE + (((k >> 3) ^ m) << 3) + (k & 7)] << 16;
      s += v.f * wr[k];
    }
    out[(size_t)(bm + m) * 10 + cl] = s;
  }
}

extern "C" void kernel_launch(void* const* d_in, const int* in_sizes, int n_in,
                              void* d_out, int out_size, void* d_ws, size_t ws_size,
                              hipStream_t stream) {
  const float* x    = (const float*)d_in[0];
  const float* W_ih = (const float*)d_in[1];
  const float* W_hh = (const float*)d_in[2];
  const float* b_ih = (const float*)d_in[3];
  const float* b_hh = (const float*)d_in[4];
  const float* fc_W = (const float*)d_in[5];
  const float* fc_b = (const float*)d_in[6];
  float* out = (float*)d_out;

  const int B = out_size / 10;            // 2048
  const int T = in_sizes[0] / (B * DD);   // 1024

  dim3 grid(B / ROWS), block(256);
  hipLaunchKernelGGL(lstm_fused, grid, block, 0, stream,
                     x, W_ih, W_hh, b_ih, b_hh, fc_W, fc_b, out, T);
}

// Round 6
// 457.718 us; speedup vs baseline: 1.4611x; 1.0595x over previous
//
#include <hip/hip_runtime.h>
#include <hip/hip_bf16.h>
#include <stdint.h>

#define DD 32       // input dim
#define HH 64       // hidden dim
#define ROWS 4      // batch rows per block (M=16 MFMA tile, A-rows duplicated x4)
#define HSTRIDE 80  // LDS h-row stride in elems (160B)
#define LOG2E 1.44269504088896340736f

typedef float f32x4 __attribute__((ext_vector_type(4)));
typedef short s16x8 __attribute__((ext_vector_type(8)));

// Single-instruction packed f32->bf16 (RNE). Low 16 bits = lo, high = hi.
__device__ __forceinline__ uint32_t cvtpk(float lo, float hi) {
  uint32_t r;
  asm("v_cvt_pk_bf16_f32 %0, %1, %2" : "=v"(r) : "v"(lo), "v"(hi));
  return r;
}

// Relaxed workgroup barrier: order LDS ops only; x-prefetch global loads stay
// in flight across timestep boundaries.
#define BAR() asm volatile("s_waitcnt lgkmcnt(0)\n\ts_barrier" ::: "memory")

__global__ __launch_bounds__(256, 2)
void lstm_fused(const float* __restrict__ x,
                const float* __restrict__ W_ih,
                const float* __restrict__ W_hh,
                const float* __restrict__ b_ih,
                const float* __restrict__ b_hh,
                const float* __restrict__ fc_W,
                const float* __restrict__ fc_b,
                float* __restrict__ out,
                int T)
{
  const int tid  = threadIdx.x;
  const int g    = tid >> 6;     // wave 0..3 -> 16-column gate group
  const int lane = tid & 63;
  const int lr   = lane & 15;    // A/D col index within tile
  const int lq   = lane >> 4;    // k-group 0..3; ALSO this lane's cell row
  const int bm   = blockIdx.x * ROWS;
  const int arow = lr & 3;       // batch row this lane's A-slot holds (dup x4)

  __shared__ __align__(16) uint16_t hbuf[2][ROWS * HSTRIDE]; // bf16 h, dbuf, swizzled

  // ---- persistent weights as B fragments, pre-scaled by log2e (2*log2e for g) ----
  const int h0 = 16 * g + lr;    // this lane's hidden column
  s16x8 Bx[4], Bh0[4], Bh1[4];
  f32x4 biasv[4];
  #pragma unroll
  for (int j = 0; j < 4; ++j) {
    const int n = 64 * j + h0;
    const float sc = (j == 2) ? (2.0f * LOG2E) : LOG2E;
    {
      const float* p = W_ih + n * DD + lq * 8;
      f32x4 a = *(const f32x4*)p;
      f32x4 b = *(const f32x4*)(p + 4);
      union { uint32_t u[4]; s16x8 s; } pk;
      pk.u[0] = cvtpk(a[0]*sc, a[1]*sc); pk.u[1] = cvtpk(a[2]*sc, a[3]*sc);
      pk.u[2] = cvtpk(b[0]*sc, b[1]*sc); pk.u[3] = cvtpk(b[2]*sc, b[3]*sc);
      Bx[j] = pk.s;
    }
    {
      const float* p = W_hh + n * HH + lq * 8;
      f32x4 a = *(const f32x4*)p;
      f32x4 b = *(const f32x4*)(p + 4);
      union { uint32_t u[4]; s16x8 s; } pk;
      pk.u[0] = cvtpk(a[0]*sc, a[1]*sc); pk.u[1] = cvtpk(a[2]*sc, a[3]*sc);
      pk.u[2] = cvtpk(b[0]*sc, b[1]*sc); pk.u[3] = cvtpk(b[2]*sc, b[3]*sc);
      Bh0[j] = pk.s;
    }
    {
      const float* p = W_hh + n * HH + 32 + lq * 8;
      f32x4 a = *(const f32x4*)p;
      f32x4 b = *(const f32x4*)(p + 4);
      union { uint32_t u[4]; s16x8 s; } pk;
      pk.u[0] = cvtpk(a[0]*sc, a[1]*sc); pk.u[1] = cvtpk(a[2]*sc, a[3]*sc);
      pk.u[2] = cvtpk(b[0]*sc, b[1]*sc); pk.u[3] = cvtpk(b[2]*sc, b[3]*sc);
      Bh1[j] = pk.s;
    }
    const float bb = (b_ih[n] + b_hh[n]) * sc;
    biasv[j] = (f32x4){bb, bb, bb, bb};
  }

  for (int i = tid; i < 2 * ROWS * HSTRIDE; i += 256) ((uint16_t*)hbuf)[i] = 0;

  float c = 0.f;  // this lane's single cell: (row=lq, col=h0)

  // hoisted LDS offsets (loop-invariant)
  const int roff0 = arow * HSTRIDE + (((lq    ) ^ arow) << 3);
  const int roff1 = arow * HSTRIDE + (((lq + 4) ^ arow) << 3);
  const int woff  = lq * HSTRIDE + (((h0 >> 3) ^ lq) << 3) + (h0 & 7);

  // 2-deep x prefetch with a single running pointer
  const float* xbase = x + (size_t)(bm + arow) * (size_t)T * DD + lq * 8;
  f32x4 xa0 = *(const f32x4*)xbase;
  f32x4 xb0 = *(const f32x4*)(xbase + 4);
  f32x4 xa1 = *(const f32x4*)(xbase + DD);
  f32x4 xb1 = *(const f32x4*)(xbase + DD + 4);
  const float* xp = xbase + 2 * DD;

  __syncthreads();

  auto step = [&](f32x4& xa, f32x4& xb, bool pf,
                  const uint16_t* __restrict__ hr, uint16_t* __restrict__ hw) {
    // pack current x into A fragment (4 cvt_pk), then issue t+2 prefetch
    union { uint32_t u[4]; s16x8 s; } ax;
    ax.u[0] = cvtpk(xa[0], xa[1]); ax.u[1] = cvtpk(xa[2], xa[3]);
    ax.u[2] = cvtpk(xb[0], xb[1]); ax.u[3] = cvtpk(xb[2], xb[3]);
    if (pf) {
      xa = *(const f32x4*)xp;
      xb = *(const f32x4*)(xp + 4);
      xp += DD;
    }
    // x-part MFMAs (h-independent; overlap other waves' tail of prev step)
    f32x4 acc[4];
    #pragma unroll
    for (int j = 0; j < 4; ++j)
      acc[j] = __builtin_amdgcn_mfma_f32_16x16x32_bf16(ax.s, Bx[j], biasv[j], 0, 0, 0);

    BAR();  // lgkmcnt-only: prev step's h writes visible, x loads stay in flight

    s16x8 ah0 = *(const s16x8*)(hr + roff0);
    s16x8 ah1 = *(const s16x8*)(hr + roff1);
    #pragma unroll
    for (int j = 0; j < 4; ++j)
      acc[j] = __builtin_amdgcn_mfma_f32_16x16x32_bf16(ah0, Bh0[j], acc[j], 0, 0, 0);
    #pragma unroll
    for (int j = 0; j < 4; ++j)
      acc[j] = __builtin_amdgcn_mfma_f32_16x16x32_bf16(ah1, Bh1[j], acc[j], 0, 0, 0);

    // acc[j][r] = gate j, batch row r, col h0 (identical across lq groups).
    // Lane's cell: (row lq, col h0) -> select acc[j][lq] via cndmask tree.
    float gj[4];
    #pragma unroll
    for (int j = 0; j < 4; ++j) {
      float s01 = (lq & 1) ? acc[j][1] : acc[j][0];
      float s23 = (lq & 1) ? acc[j][3] : acc[j][2];
      gj[j] = (lq & 2) ? s23 : s01;
    }

    // single-cell LSTM update (weights pre-scaled by log2e)
    float ig = __builtin_amdgcn_rcpf(1.f + __builtin_amdgcn_exp2f(-gj[0]));
    float fg = __builtin_amdgcn_rcpf(1.f + __builtin_amdgcn_exp2f(-gj[1]));
    float gt = 1.f - 2.f * __builtin_amdgcn_rcpf(1.f + __builtin_amdgcn_exp2f(gj[2]));
    float og = __builtin_amdgcn_rcpf(1.f + __builtin_amdgcn_exp2f(-gj[3]));
    c = fg * c + ig * gt;
    float tc = 1.f - 2.f * __builtin_amdgcn_rcpf(
                 1.f + __builtin_amdgcn_exp2f((2.0f * LOG2E) * c));
    float hv = og * tc;
    hw[woff] = (uint16_t)cvtpk(hv, hv);  // one b16 write per lane
  };

  for (int t = 0; t < T - 2; t += 2) {
    step(xa0, xb0, true, hbuf[0], hbuf[1]);
    step(xa1, xb1, true, hbuf[1], hbuf[0]);
  }
  step(xa0, xb0, false, hbuf[0], hbuf[1]);
  step(xa1, xb1, false, hbuf[1], hbuf[0]);

  __syncthreads();  // final h (bf16) in hbuf[0]

  // ---- epilogue: logits = h_last @ fc_W^T + fc_b ----
  if (tid < ROWS * 10) {
    const int m = tid / 10, cl = tid % 10;
    float s = fc_b[cl];
    const float* wr = fc_W + cl * HH;
    #pragma unroll
    for (int k = 0; k < HH; ++k) {
      union { uint32_t u; float f; } v;
      v.u = (uint32_t)hbuf[0][m * HSTRIDE + (((k >> 3) ^ m) << 3) + (k & 7)] << 16;
      s += v.f * wr[k];
    }
    out[(size_t)(bm + m) * 10 + cl] = s;
  }
}

extern "C" void kernel_launch(void* const* d_in, const int* in_sizes, int n_in,
                              void* d_out, int out_size, void* d_ws, size_t ws_size,
                              hipStream_t stream) {
  const float* x    = (const float*)d_in[0];
  const float* W_ih = (const float*)d_in[1];
  const float* W_hh = (const float*)d_in[2];
  const float* b_ih = (const float*)d_in[3];
  const float* b_hh = (const float*)d_in[4];
  const float* fc_W = (const float*)d_in[5];
  const float* fc_b = (const float*)d_in[6];
  float* out = (float*)d_out;

  const int B = out_size / 10;            // 2048
  const int T = in_sizes[0] / (B * DD);   // 1024

  dim3 grid(B / ROWS), block(256);
  hipLaunchKernelGGL(lstm_fused, grid, block, 0, stream,
                     x, W_ih, W_hh, b_ih, b_hh, fc_W, fc_b, out, T);
}